// Round 22
// baseline (342.917 us; speedup 1.0000x reference)
//
#include <hip/hip_runtime.h>

// Round 22: 256x256 tile / 8-wave (512-thread) blocks for TERMS=1 (QK, PV).
// R21 proof: QK/PV latency/barrier-bound (HBM 7%, MfmaUtil 30%). Intensity
// per K-step: 48KB->4.2MF (87 F/B) becomes 64KB->8.4MF (131 F/B). Per-wave
// geometry unchanged (128x64 out, acc[8][4], same k-order -> absmax
// bit-identical). proj (TERMS=2, 256 thr) / softmax / prep = R21 (317.4us).

typedef __attribute__((ext_vector_type(8))) _Float16 f16x8;
typedef __attribute__((ext_vector_type(4))) float f32x4;
typedef unsigned short u16;
typedef unsigned int u32;

#define B_ 8
#define SQL 2048
#define SKL 2048
#define DD 1024
#define NEGC -1000000000.0f

static __device__ __forceinline__ u16 f2h(float x) {
  _Float16 h = (_Float16)x;                       // v_cvt_f16_f32, RNE
  return __builtin_bit_cast(u16, h);
}
static __device__ __forceinline__ float h2f(u16 v) {
  return (float)__builtin_bit_cast(_Float16, v);
}
static __device__ __forceinline__ void gload16(const void* g, void* l) {
  __builtin_amdgcn_global_load_lds((const __attribute__((address_space(1))) u32*)g,
                                   (__attribute__((address_space(3))) u32*)l, 16, 0, 0);
}

// ---------------- convert fp32 -> fp16 (single) ----------------
__global__ __launch_bounds__(256) void cvt16_k(const float* __restrict__ in,
                                               u16* __restrict__ out, long n) {
  long i = ((long)blockIdx.x * 256 + threadIdx.x) * 8;
  long stride = (long)gridDim.x * 256 * 8;
  for (; i < n; i += stride) {
    float4 v0 = *(const float4*)(in + i);
    float4 v1 = *(const float4*)(in + i + 4);
    ushort4 o0 = make_ushort4(f2h(v0.x), f2h(v0.y), f2h(v0.z), f2h(v0.w));
    ushort4 o1 = make_ushort4(f2h(v1.x), f2h(v1.y), f2h(v1.z), f2h(v1.w));
    *(ushort4*)(out + i) = o0;
    *(ushort4*)(out + i + 4) = o1;
  }
}

// ---------------- split fp32 -> fp16 hi + fp16 lo (for W) ----------------
__global__ __launch_bounds__(256) void split16_k(const float* __restrict__ in,
                                                 u16* __restrict__ hi, u16* __restrict__ lo,
                                                 long n) {
  long i = ((long)blockIdx.x * 256 + threadIdx.x) * 4;
  long stride = (long)gridDim.x * 256 * 4;
  for (; i < n; i += stride) {
    float4 v = *(const float4*)(in + i);
    u16 h0 = f2h(v.x), h1 = f2h(v.y), h2 = f2h(v.z), h3 = f2h(v.w);
    *(ushort4*)(hi + i) = make_ushort4(h0, h1, h2, h3);
    *(ushort4*)(lo + i) = make_ushort4(f2h(v.x - h2f(h0)), f2h(v.y - h2f(h1)),
                                       f2h(v.z - h2f(h2)), f2h(v.w - h2f(h3)));
  }
}

// ---------------- fused mem: fp32 [Sk][D] -> memh fp16 + memT fp16 [D][Sk] ----------------
__global__ __launch_bounds__(256) void split_mem16_k(const float* __restrict__ in,
                                                     u16* __restrict__ hi,
                                                     u16* __restrict__ trn) {
  __shared__ u16 t[64][65];
  long bo = (long)blockIdx.z * SKL * DD;
  int r0 = blockIdx.y * 64, c0 = blockIdx.x * 64;
  int tr = threadIdx.x / 16, tc4 = (threadIdx.x % 16) * 4;
#pragma unroll
  for (int i = 0; i < 4; ++i) {
    int r = tr + i * 16;
    long idx = bo + (long)(r0 + r) * DD + c0 + tc4;
    float4 v = *(const float4*)(in + idx);
    u16 h0 = f2h(v.x), h1 = f2h(v.y), h2 = f2h(v.z), h3 = f2h(v.w);
    *(ushort4*)(hi + idx) = make_ushort4(h0, h1, h2, h3);
    t[r][tc4 + 0] = h0; t[r][tc4 + 1] = h1; t[r][tc4 + 2] = h2; t[r][tc4 + 3] = h3;
  }
  __syncthreads();
#pragma unroll
  for (int i = 0; i < 4; ++i) {
    int c = tr + i * 16;   // output row = original column c0+c
    ushort4 v = make_ushort4(t[tc4 + 0][c], t[tc4 + 1][c], t[tc4 + 2][c], t[tc4 + 3][c]);
    *(ushort4*)(trn + bo + (long)(c0 + c) * SKL + r0 + tc4) = v;
  }
}

// ---------------- unified B^T-layout fp16 MFMA GEMM ----------------
// C[m][n] = sum_k A[m][k]*B[n][k]; BK=64, single-buffer LDS,
// mfma_f32_16x16x32_f16, XOR-swizzled via pre-swizzled global source,
// batch-folded 1-D grid with bijective XCD-chunk swizzle.
// TERMS=1: 256x256 tile, 512 thr / 8 waves (2x4), 64KB LDS.   QK/PV
// TERMS=2: 256x128 tile, 256 thr / 4 waves (2x2), B dual.     proj
// Per-wave output = 128x64 (acc[8][4]) in both configs.
// OUTMODE: 0 = fp32 ; 1 = fp16 single
template <int TERMS, int OUTMODE, bool BIAS>
__global__ __launch_bounds__((TERMS == 1) ? 512 : 256, 2) void gemm_f16(
    const u16* __restrict__ Ah,
    const u16* __restrict__ Bh, const u16* __restrict__ Bl,
    const float* __restrict__ bias,
    void* __restrict__ C0,
    int N, int K, int TPB,   // TPB = tiles per batch
    long batchA, long batchB, long batchC) {
  constexpr int BM = 256;
  constexpr int BN = (TERMS == 1) ? 256 : 128;
  constexpr int MF = 8;                            // M fragments per wave
  constexpr int BROWS = (TERMS == 1) ? 256 : 128;  // B LDS rows
  constexpr int RWB = (TERMS == 2) ? 128 : 64;     // u16 per B LDS row
  constexpr int NT = (TERMS == 1) ? 512 : 256;     // threads
  __shared__ u16 lA[BM * 64];
  __shared__ u16 lB[BROWS * RWB];

  // ---- batch-folded bijective XCD swizzle (gridDim.x % 8 == 0) ----
  const int nwg = gridDim.x;
  int id = blockIdx.x;
  int j = (id & 7) * (nwg >> 3) + (id >> 3);
  const int TX = N / BN;
  const int bz = j / TPB;
  const int r0_ = j % TPB;
  const int by = r0_ / TX, bx = r0_ % TX;

  const u16* pAh = Ah + (long)bz * batchA;
  const u16* pBh = Bh + (long)bz * batchB;
  const u16* pBl = (TERMS == 2) ? Bl : nullptr;   // proj W has no batch

  const int tid = threadIdx.x;
  const int l = tid & 63, w = tid >> 6;
  const int wr = (TERMS == 1) ? (w >> 2) : (w >> 1);
  const int wc = (TERMS == 1) ? (w & 3) : (w & 1);
  const long am0 = (long)by * BM;
  const long bn0 = (long)bx * BN;

  f32x4 acc[MF][4];
#pragma unroll
  for (int i = 0; i < MF; ++i)
#pragma unroll
    for (int j2 = 0; j2 < 4; ++j2) {
      f32x4 z = {0.f, 0.f, 0.f, 0.f};
      acc[i][j2] = z;
    }

  const int lrow = l & 15, lch = l >> 4;

  for (int k0 = 0; k0 < K; k0 += 64) {
    __syncthreads();
    // ---- A stage: single fp16, 8 chunks/row (proven involution) ----
#pragma unroll
    for (int i = 0; i < BM * 8 / NT; ++i) {
      int row = i * (NT / 8) + (tid >> 3);
      int cc = (tid & 7) ^ (row & 7);
      gload16(pAh + (am0 + row) * K + k0 + cc * 8, &lA[row * 64 + (tid & 7) * 8]);
    }
    // ---- B stage ----
    if (TERMS == 2) {
#pragma unroll
      for (int i = 0; i < 8; ++i) {
        int row = i * 16 + (tid >> 4);
        int s = tid & 15;
        int cc = s ^ (row & 15);
        const u16* src = (cc < 8) ? (pBh + (bn0 + row) * K + k0 + cc * 8)
                                  : (pBl + (bn0 + row) * K + k0 + (cc - 8) * 8);
        gload16(src, &lB[row * 128 + s * 8]);
      }
    } else {
#pragma unroll
      for (int i = 0; i < 4; ++i) {
        int row = i * 64 + (tid >> 3);
        int cc = (tid & 7) ^ (row & 7);
        gload16(pBh + (bn0 + row) * K + k0 + cc * 8, &lB[row * 64 + (tid & 7) * 8]);
      }
    }
    __syncthreads();

#pragma unroll
    for (int kk = 0; kk < 2; ++kk) {
      if (TERMS == 2) {
        f16x8 ah[8], bh[4], bl_[4];
#pragma unroll
        for (int f = 0; f < 8; ++f) {
          int ra = wr * 128 + f * 16 + lrow;
          int c = kk * 4 + lch;
          ah[f] = *(const f16x8*)&lA[ra * 64 + (c ^ (ra & 7)) * 8];
        }
#pragma unroll
        for (int f = 0; f < 4; ++f) {
          int rb = wc * 64 + f * 16 + lrow;
          int c = kk * 4 + lch;
          bh[f] = *(const f16x8*)&lB[rb * 128 + (c ^ (rb & 15)) * 8];
          bl_[f] = *(const f16x8*)&lB[rb * 128 + ((8 + c) ^ (rb & 15)) * 8];
        }
#pragma unroll
        for (int mf = 0; mf < 8; ++mf)
#pragma unroll
          for (int nf = 0; nf < 4; ++nf) {
            acc[mf][nf] = __builtin_amdgcn_mfma_f32_16x16x32_f16(ah[mf], bh[nf], acc[mf][nf], 0, 0, 0);
            acc[mf][nf] = __builtin_amdgcn_mfma_f32_16x16x32_f16(ah[mf], bl_[nf], acc[mf][nf], 0, 0, 0);
          }
      } else {
        f16x8 ah[8], bh[4];
#pragma unroll
        for (int f = 0; f < 8; ++f) {
          int ra = wr * 128 + f * 16 + lrow;
          int c = kk * 4 + lch;
          ah[f] = *(const f16x8*)&lA[ra * 64 + (c ^ (ra & 7)) * 8];
        }
#pragma unroll
        for (int f = 0; f < 4; ++f) {
          int rb = wc * 64 + f * 16 + lrow;
          int c = kk * 4 + lch;
          bh[f] = *(const f16x8*)&lB[rb * 64 + (c ^ (rb & 7)) * 8];
        }
#pragma unroll
        for (int mf = 0; mf < 8; ++mf)
#pragma unroll
          for (int nf = 0; nf < 4; ++nf)
            acc[mf][nf] = __builtin_amdgcn_mfma_f32_16x16x32_f16(ah[mf], bh[nf], acc[mf][nf], 0, 0, 0);
      }
    }
  }

  // epilogue: C/D layout col = lane&15, row = (lane>>4)*4 + reg
#pragma unroll
  for (int mf = 0; mf < MF; ++mf)
#pragma unroll
    for (int nf = 0; nf < 4; ++nf)
#pragma unroll
      for (int r = 0; r < 4; ++r) {
        long row = am0 + wr * 128 + mf * 16 + (l >> 4) * 4 + r;
        long col = bn0 + wc * 64 + nf * 16 + (l & 15);
        float v = acc[mf][nf][r];
        if (BIAS) v += bias[col];
        long idx = (long)bz * batchC + row * N + col;
        if (OUTMODE == 0) ((float*)C0)[idx] = v;
        else              ((u16*)C0)[idx] = f2h(v);
      }
}

// ---------------- mask + row softmax, wave-per-row (no barriers/LDS) ----------------
__global__ __launch_bounds__(256) void softmax16_k(const float* __restrict__ S,
                                                   const int* __restrict__ M,
                                                   u16* __restrict__ P) {
  long row = (long)blockIdx.x * 4 + (threadIdx.x >> 6);
  const float* s = S + row * SKL;
  const int* m = M + row * SKL;
  u16* p = P + row * SKL;
  const int lane = threadIdx.x & 63;
  float x[32];
#pragma unroll
  for (int j = 0; j < 8; ++j) {
    float4 v = *(const float4*)(s + lane * 4 + j * 256);
    int4 q = *(const int4*)(m + lane * 4 + j * 256);
    x[j * 4 + 0] = q.x ? v.x : v.x + NEGC;
    x[j * 4 + 1] = q.y ? v.y : v.y + NEGC;
    x[j * 4 + 2] = q.z ? v.z : v.z + NEGC;
    x[j * 4 + 3] = q.w ? v.w : v.w + NEGC;
  }
  float mx = x[0];
#pragma unroll
  for (int j = 1; j < 32; ++j) mx = fmaxf(mx, x[j]);
#pragma unroll
  for (int o = 32; o >= 1; o >>= 1) mx = fmaxf(mx, __shfl_xor(mx, o, 64));
  float sum = 0.f;
#pragma unroll
  for (int j = 0; j < 32; ++j) { x[j] = __expf(x[j] - mx); sum += x[j]; }
#pragma unroll
  for (int o = 32; o >= 1; o >>= 1) sum += __shfl_xor(sum, o, 64);
  float inv = 1.f / sum;
#pragma unroll
  for (int j = 0; j < 8; ++j) {
    ushort4 o4 = make_ushort4(f2h(x[j * 4 + 0] * inv), f2h(x[j * 4 + 1] * inv),
                              f2h(x[j * 4 + 2] * inv), f2h(x[j * 4 + 3] * inv));
    *(ushort4*)(p + lane * 4 + j * 256) = o4;
  }
}

extern "C" void kernel_launch(void* const* d_in, const int* in_sizes, int n_in,
                              void* d_out, int out_size, void* d_ws, size_t ws_size,
                              hipStream_t stream) {
  const float* query = (const float*)d_in[0];
  const float* mem = (const float*)d_in[1];
  const int* mask = (const int*)d_in[2];
  const float* Wm = (const float*)d_in[3];
  const float* bias = (const float*)d_in[4];
  float* out = (float*)d_out;   // fp32 output

  const long nQ = (long)B_ * SQL * DD;   // 16.7M
  const long nW = (long)DD * DD;
  const long nS = (long)B_ * SQL * SKL;

  char* ws = (char*)d_ws;
  u16* q16 = (u16*)ws; ws += nQ * 2;    // fp16(query); becomes P after proj+QK
  u16* memh = (u16*)ws; ws += nQ * 2;
  u16* memT = (u16*)ws; ws += nQ * 2;
  u16* q1 = (u16*)ws; ws += nQ * 2;     // projected q, fp16
  u16* wh = (u16*)ws; ws += nW * 2;
  u16* wl = (u16*)ws; ws += nW * 2;
  float* S = (float*)ws; ws += nS * 4;
  u16* P = q16;   // q16 dead after projection

  cvt16_k<<<2048, 256, 0, stream>>>(query, q16, nQ);
  split16_k<<<512, 256, 0, stream>>>(Wm, wh, wl, nW);
  split_mem16_k<<<dim3(DD / 64, SKL / 64, B_), 256, 0, stream>>>(mem, memh, memT);

  // projection (2-term, 256x128, 256 thr): grid = 64 x 8 = 512
  gemm_f16<2, 1, true><<<512, 256, 0, stream>>>(
      q16, wh, wl, bias, q1, DD, DD, 512, 0, 0, 0);
  // logits (1-term, 256x256, 512 thr): per batch 8 x 8 -> grid 512
  gemm_f16<1, 0, false><<<512, 512, 0, stream>>>(
      q1, memh, nullptr, nullptr, S, SKL, DD, 64,
      (long)SQL * DD, (long)SKL * DD, (long)SQL * SKL);
  // mask + softmax -> P fp16 (wave-per-row)
  softmax16_k<<<(B_ * SQL) / 4, 256, 0, stream>>>(S, mask, P);
  // PV (1-term, 256x256, 512 thr): per batch 8 x 4 -> grid 256
  gemm_f16<1, 0, false><<<256, 512, 0, stream>>>(
      P, memT, nullptr, nullptr, out, DD, SKL, 32,
      (long)SQL * SKL, (long)DD * SKL, (long)SQL * DD);
}

// Round 23
// 314.694 us; speedup vs baseline: 1.0897x; 1.0897x over previous
//
#include <hip/hip_runtime.h>

// Round 23: revert R22's 256x256 (8-wave barrier cost > intensity gain; tile
// dimension exhausted both directions). Back to R21 GEMM config (best: 317us).
// New: GRID-FUSE independent kernels to overlap serial dispatches:
//   fused1 = cvt16(query) + split16(W)      (independent of each other)
//   fused2 = proj (blocks 0-511) + split_mem (blocks 512-4607)  (disjoint I/O;
//            split_mem BW work backfills CUs as proj blocks retire)
// QK / softmax / PV identical to R21.

typedef __attribute__((ext_vector_type(8))) _Float16 f16x8;
typedef __attribute__((ext_vector_type(4))) float f32x4;
typedef unsigned short u16;
typedef unsigned int u32;

#define B_ 8
#define SQL 2048
#define SKL 2048
#define DD 1024
#define NEGC -1000000000.0f

static __device__ __forceinline__ u16 f2h(float x) {
  _Float16 h = (_Float16)x;                       // v_cvt_f16_f32, RNE
  return __builtin_bit_cast(u16, h);
}
static __device__ __forceinline__ float h2f(u16 v) {
  return (float)__builtin_bit_cast(_Float16, v);
}
static __device__ __forceinline__ void gload16(const void* g, void* l) {
  __builtin_amdgcn_global_load_lds((const __attribute__((address_space(1))) u32*)g,
                                   (__attribute__((address_space(3))) u32*)l, 16, 0, 0);
}

// ---------------- fused1: cvt16(query) [blocks 0..2047] + split16(W) [2048..2559] ----------------
__global__ __launch_bounds__(256) void prep_k(const float* __restrict__ query,
                                              u16* __restrict__ q16,
                                              const float* __restrict__ Wm,
                                              u16* __restrict__ wh, u16* __restrict__ wl) {
  if (blockIdx.x < 2048) {
    long n = (long)B_ * SQL * DD;
    long i = ((long)blockIdx.x * 256 + threadIdx.x) * 8;
    long stride = 2048L * 256 * 8;
    for (; i < n; i += stride) {
      float4 v0 = *(const float4*)(query + i);
      float4 v1 = *(const float4*)(query + i + 4);
      ushort4 o0 = make_ushort4(f2h(v0.x), f2h(v0.y), f2h(v0.z), f2h(v0.w));
      ushort4 o1 = make_ushort4(f2h(v1.x), f2h(v1.y), f2h(v1.z), f2h(v1.w));
      *(ushort4*)(q16 + i) = o0;
      *(ushort4*)(q16 + i + 4) = o1;
    }
  } else {
    long i = ((long)(blockIdx.x - 2048) * 256 + threadIdx.x) * 8;   // W: 1M elems
    float4 v0 = *(const float4*)(Wm + i);
    float4 v1 = *(const float4*)(Wm + i + 4);
    u16 h0 = f2h(v0.x), h1 = f2h(v0.y), h2 = f2h(v0.z), h3 = f2h(v0.w);
    u16 h4 = f2h(v1.x), h5 = f2h(v1.y), h6 = f2h(v1.z), h7 = f2h(v1.w);
    *(ushort4*)(wh + i) = make_ushort4(h0, h1, h2, h3);
    *(ushort4*)(wh + i + 4) = make_ushort4(h4, h5, h6, h7);
    *(ushort4*)(wl + i) = make_ushort4(f2h(v0.x - h2f(h0)), f2h(v0.y - h2f(h1)),
                                       f2h(v0.z - h2f(h2)), f2h(v0.w - h2f(h3)));
    *(ushort4*)(wl + i + 4) = make_ushort4(f2h(v1.x - h2f(h4)), f2h(v1.y - h2f(h5)),
                                           f2h(v1.z - h2f(h6)), f2h(v1.w - h2f(h7)));
  }
}

// ---------------- fused2: proj (256x128, TERMS=2) + split_mem ----------------
// blocks [0,512): projection q16 @ (Wh+Wl)^T + bias -> q1 fp16
// blocks [512,4608): mem fp32 -> memh fp16 + memT fp16 [D][Sk]  (64x64 tiles)
__global__ __launch_bounds__(256, 2) void proj_split_k(
    const u16* __restrict__ Ah, const u16* __restrict__ Bh, const u16* __restrict__ Bl,
    const float* __restrict__ bias, u16* __restrict__ C0,
    const float* __restrict__ mem, u16* __restrict__ memh, u16* __restrict__ memT) {
  __shared__ u16 lA[256 * 64];     // 32KB (proj A; split_mem aliases 8.3KB of it)
  __shared__ u16 lB[128 * 128];    // 32KB (proj B dual)

  if (blockIdx.x < 512) {
    // ---- projection: R21 TERMS=2 path, nwg=512 swizzle ----
    const int N = DD, K = DD;
    int id = blockIdx.x;
    int j = (id & 7) * 64 + (id >> 3);      // bijective, nwg=512
    const int TX = N >> 7;                  // 8
    const int by = j / TX, bx = j % TX;
    const int tid = threadIdx.x;
    const int l = tid & 63, w = tid >> 6;
    const int wr = w >> 1, wc = w & 1;
    const long am0 = (long)by * 256;
    const long bn0 = (long)bx * 128;

    f32x4 acc[8][4];
#pragma unroll
    for (int i = 0; i < 8; ++i)
#pragma unroll
      for (int j2 = 0; j2 < 4; ++j2) {
        f32x4 z = {0.f, 0.f, 0.f, 0.f};
        acc[i][j2] = z;
      }
    const int lrow = l & 15, lch = l >> 4;

    for (int k0 = 0; k0 < K; k0 += 64) {
      __syncthreads();
#pragma unroll
      for (int i = 0; i < 8; ++i) {
        int row = i * 32 + (tid >> 3);
        int cc = (tid & 7) ^ (row & 7);
        gload16(Ah + (am0 + row) * K + k0 + cc * 8, &lA[row * 64 + (tid & 7) * 8]);
      }
#pragma unroll
      for (int i = 0; i < 8; ++i) {
        int row = i * 16 + (tid >> 4);
        int s = tid & 15;
        int cc = s ^ (row & 15);
        const u16* src = (cc < 8) ? (Bh + (bn0 + row) * K + k0 + cc * 8)
                                  : (Bl + (bn0 + row) * K + k0 + (cc - 8) * 8);
        gload16(src, &lB[row * 128 + s * 8]);
      }
      __syncthreads();

#pragma unroll
      for (int kk = 0; kk < 2; ++kk) {
        f16x8 ah[8], bh[4], bl_[4];
#pragma unroll
        for (int f = 0; f < 8; ++f) {
          int ra = wr * 128 + f * 16 + lrow;
          int c = kk * 4 + lch;
          ah[f] = *(const f16x8*)&lA[ra * 64 + (c ^ (ra & 7)) * 8];
        }
#pragma unroll
        for (int f = 0; f < 4; ++f) {
          int rb = wc * 64 + f * 16 + lrow;
          int c = kk * 4 + lch;
          bh[f] = *(const f16x8*)&lB[rb * 128 + (c ^ (rb & 15)) * 8];
          bl_[f] = *(const f16x8*)&lB[rb * 128 + ((8 + c) ^ (rb & 15)) * 8];
        }
#pragma unroll
        for (int mf = 0; mf < 8; ++mf)
#pragma unroll
          for (int nf = 0; nf < 4; ++nf) {
            acc[mf][nf] = __builtin_amdgcn_mfma_f32_16x16x32_f16(ah[mf], bh[nf], acc[mf][nf], 0, 0, 0);
            acc[mf][nf] = __builtin_amdgcn_mfma_f32_16x16x32_f16(ah[mf], bl_[nf], acc[mf][nf], 0, 0, 0);
          }
      }
    }
#pragma unroll
    for (int mf = 0; mf < 8; ++mf)
#pragma unroll
      for (int nf = 0; nf < 4; ++nf)
#pragma unroll
        for (int r = 0; r < 4; ++r) {
          long row = am0 + wr * 128 + mf * 16 + (l >> 4) * 4 + r;
          long col = bn0 + wc * 64 + nf * 16 + (l & 15);
          C0[row * N + col] = f2h(acc[mf][nf][r] + bias[col]);
        }
  } else {
    // ---- split_mem: 64x64 transpose tiles, flattened grid (16,32,8) ----
    u16(*t)[65] = (u16(*)[65])lA;   // 64x65 u16 = 8.3KB, aliases lA
    int id2 = blockIdx.x - 512;
    int bx = id2 & 15, by = (id2 >> 4) & 31, bz = id2 >> 9;
    long bo = (long)bz * SKL * DD;
    int r0 = by * 64, c0 = bx * 64;
    int tr = threadIdx.x / 16, tc4 = (threadIdx.x % 16) * 4;
#pragma unroll
    for (int i = 0; i < 4; ++i) {
      int r = tr + i * 16;
      long idx = bo + (long)(r0 + r) * DD + c0 + tc4;
      float4 v = *(const float4*)(mem + idx);
      u16 h0 = f2h(v.x), h1 = f2h(v.y), h2 = f2h(v.z), h3 = f2h(v.w);
      *(ushort4*)(memh + idx) = make_ushort4(h0, h1, h2, h3);
      t[r][tc4 + 0] = h0; t[r][tc4 + 1] = h1; t[r][tc4 + 2] = h2; t[r][tc4 + 3] = h3;
    }
    __syncthreads();
#pragma unroll
    for (int i = 0; i < 4; ++i) {
      int c = tr + i * 16;   // output row = original column c0+c
      ushort4 v = make_ushort4(t[tc4 + 0][c], t[tc4 + 1][c], t[tc4 + 2][c], t[tc4 + 3][c]);
      *(ushort4*)(memT + bo + (long)(c0 + c) * SKL + r0 + tc4) = v;
    }
  }
}

// ---------------- TERMS=1 GEMM (QK / PV): 256x128, 4 waves, BK=64 ----------------
template <int OUTMODE>
__global__ __launch_bounds__(256, 2) void gemm1_f16(
    const u16* __restrict__ Ah, const u16* __restrict__ Bh,
    void* __restrict__ C0,
    int N, int K, int TPB, long batchA, long batchB, long batchC) {
  __shared__ u16 lA[256 * 64];
  __shared__ u16 lB[128 * 64];

  const int nwg = gridDim.x;
  int id = blockIdx.x;
  int j = (id & 7) * (nwg >> 3) + (id >> 3);
  const int TX = N >> 7;
  const int bz = j / TPB;
  const int r0_ = j % TPB;
  const int by = r0_ / TX, bx = r0_ % TX;

  const u16* pAh = Ah + (long)bz * batchA;
  const u16* pBh = Bh + (long)bz * batchB;

  const int tid = threadIdx.x;
  const int l = tid & 63, w = tid >> 6;
  const int wr = w >> 1, wc = w & 1;
  const long am0 = (long)by * 256;
  const long bn0 = (long)bx * 128;

  f32x4 acc[8][4];
#pragma unroll
  for (int i = 0; i < 8; ++i)
#pragma unroll
    for (int j2 = 0; j2 < 4; ++j2) {
      f32x4 z = {0.f, 0.f, 0.f, 0.f};
      acc[i][j2] = z;
    }
  const int lrow = l & 15, lch = l >> 4;

  for (int k0 = 0; k0 < K; k0 += 64) {
    __syncthreads();
#pragma unroll
    for (int i = 0; i < 8; ++i) {
      int row = i * 32 + (tid >> 3);
      int cc = (tid & 7) ^ (row & 7);
      gload16(pAh + (am0 + row) * K + k0 + cc * 8, &lA[row * 64 + (tid & 7) * 8]);
    }
#pragma unroll
    for (int i = 0; i < 4; ++i) {
      int row = i * 32 + (tid >> 3);
      int cc = (tid & 7) ^ (row & 7);
      gload16(pBh + (bn0 + row) * K + k0 + cc * 8, &lB[row * 64 + (tid & 7) * 8]);
    }
    __syncthreads();

#pragma unroll
    for (int kk = 0; kk < 2; ++kk) {
      f16x8 ah[8], bh[4];
#pragma unroll
      for (int f = 0; f < 8; ++f) {
        int ra = wr * 128 + f * 16 + lrow;
        int c = kk * 4 + lch;
        ah[f] = *(const f16x8*)&lA[ra * 64 + (c ^ (ra & 7)) * 8];
      }
#pragma unroll
      for (int f = 0; f < 4; ++f) {
        int rb = wc * 64 + f * 16 + lrow;
        int c = kk * 4 + lch;
        bh[f] = *(const f16x8*)&lB[rb * 64 + (c ^ (rb & 7)) * 8];
      }
#pragma unroll
      for (int mf = 0; mf < 8; ++mf)
#pragma unroll
        for (int nf = 0; nf < 4; ++nf)
          acc[mf][nf] = __builtin_amdgcn_mfma_f32_16x16x32_f16(ah[mf], bh[nf], acc[mf][nf], 0, 0, 0);
    }
  }

#pragma unroll
  for (int mf = 0; mf < 8; ++mf)
#pragma unroll
    for (int nf = 0; nf < 4; ++nf)
#pragma unroll
      for (int r = 0; r < 4; ++r) {
        long row = am0 + wr * 128 + mf * 16 + (l >> 4) * 4 + r;
        long col = bn0 + wc * 64 + nf * 16 + (l & 15);
        long idx = (long)bz * batchC + row * N + col;
        if (OUTMODE == 0) ((float*)C0)[idx] = acc[mf][nf][r];
        else              ((u16*)C0)[idx] = f2h(acc[mf][nf][r]);
      }
}

// ---------------- mask + row softmax, wave-per-row (no barriers/LDS) ----------------
__global__ __launch_bounds__(256) void softmax16_k(const float* __restrict__ S,
                                                   const int* __restrict__ M,
                                                   u16* __restrict__ P) {
  long row = (long)blockIdx.x * 4 + (threadIdx.x >> 6);
  const float* s = S + row * SKL;
  const int* m = M + row * SKL;
  u16* p = P + row * SKL;
  const int lane = threadIdx.x & 63;
  float x[32];
#pragma unroll
  for (int j = 0; j < 8; ++j) {
    float4 v = *(const float4*)(s + lane * 4 + j * 256);
    int4 q = *(const int4*)(m + lane * 4 + j * 256);
    x[j * 4 + 0] = q.x ? v.x : v.x + NEGC;
    x[j * 4 + 1] = q.y ? v.y : v.y + NEGC;
    x[j * 4 + 2] = q.z ? v.z : v.z + NEGC;
    x[j * 4 + 3] = q.w ? v.w : v.w + NEGC;
  }
  float mx = x[0];
#pragma unroll
  for (int j = 1; j < 32; ++j) mx = fmaxf(mx, x[j]);
#pragma unroll
  for (int o = 32; o >= 1; o >>= 1) mx = fmaxf(mx, __shfl_xor(mx, o, 64));
  float sum = 0.f;
#pragma unroll
  for (int j = 0; j < 32; ++j) { x[j] = __expf(x[j] - mx); sum += x[j]; }
#pragma unroll
  for (int o = 32; o >= 1; o >>= 1) sum += __shfl_xor(sum, o, 64);
  float inv = 1.f / sum;
#pragma unroll
  for (int j = 0; j < 8; ++j) {
    ushort4 o4 = make_ushort4(f2h(x[j * 4 + 0] * inv), f2h(x[j * 4 + 1] * inv),
                              f2h(x[j * 4 + 2] * inv), f2h(x[j * 4 + 3] * inv));
    *(ushort4*)(p + lane * 4 + j * 256) = o4;
  }
}

extern "C" void kernel_launch(void* const* d_in, const int* in_sizes, int n_in,
                              void* d_out, int out_size, void* d_ws, size_t ws_size,
                              hipStream_t stream) {
  const float* query = (const float*)d_in[0];
  const float* mem = (const float*)d_in[1];
  const int* mask = (const int*)d_in[2];
  const float* Wm = (const float*)d_in[3];
  const float* bias = (const float*)d_in[4];
  float* out = (float*)d_out;   // fp32 output

  const long nQ = (long)B_ * SQL * DD;   // 16.7M
  const long nW = (long)DD * DD;
  const long nS = (long)B_ * SQL * SKL;

  char* ws = (char*)d_ws;
  u16* q16 = (u16*)ws; ws += nQ * 2;    // fp16(query); becomes P after proj+QK
  u16* memh = (u16*)ws; ws += nQ * 2;
  u16* memT = (u16*)ws; ws += nQ * 2;
  u16* q1 = (u16*)ws; ws += nQ * 2;     // projected q, fp16
  u16* wh = (u16*)ws; ws += nW * 2;
  u16* wl = (u16*)ws; ws += nW * 2;
  float* S = (float*)ws; ws += nS * 4;
  u16* P = q16;   // q16 dead after projection

  // fused1: cvt16(query) + split16(W)
  prep_k<<<2048 + 512, 256, 0, stream>>>(query, q16, Wm, wh, wl);
  // fused2: proj (blocks 0-511) + split_mem (blocks 512-4607)
  proj_split_k<<<512 + 4096, 256, 0, stream>>>(q16, wh, wl, bias, q1, mem, memh, memT);
  // logits (1-term, 256x128): per batch 8x16 -> grid 1024
  gemm1_f16<0><<<1024, 256, 0, stream>>>(
      q1, memh, S, SKL, DD, 128,
      (long)SQL * DD, (long)SKL * DD, (long)SQL * SKL);
  // mask + softmax -> P fp16 (wave-per-row)
  softmax16_k<<<(B_ * SQL) / 4, 256, 0, stream>>>(S, mask, P);
  // PV (1-term, 256x128): per batch 8x8 -> grid 512
  gemm1_f16<0><<<512, 256, 0, stream>>>(
      P, memT, out, DD, SKL, 64,
      (long)SQL * SKL, (long)DD * SKL, (long)SQL * DD);
}